// Round 6
// baseline (136.735 us; speedup 1.0000x reference)
//
#include <hip/hip_runtime.h>
#include <hip/hip_bf16.h>
#include <math.h>

#define BATCH 64
#define DIM 1024
#define NROW (BATCH * DIM)        // 65536 rows of C
// d_out layout (floats): h[65536] | C_new[67108864] | n_new[65536] | m_new[65536]
#define OFF_H 0
#define OFF_C 65536
#define OFF_N (65536 + 67108864)
#define OFF_M (OFF_N + 65536)

typedef float f4     __attribute__((ext_vector_type(4)));
typedef float f32x4  __attribute__((ext_vector_type(4)));   // MFMA C/D frag
typedef short bf16x8 __attribute__((ext_vector_type(8)));   // MFMA A/B frag (8 bf16)

// ws layout (floats): pre[6][NROW], gate order 0:q 1:k 2:v 3:i 4:f 5:o

__device__ inline short f2bf(float v) {
    __hip_bfloat16 h = __float2bfloat16(v);   // RNE convert
    short s;
    __builtin_memcpy(&s, &h, 2);
    return s;
}

__device__ inline bf16x8 load_bf8(const float* __restrict__ p) {
    f4 a = *reinterpret_cast<const f4*>(p);
    f4 b = *reinterpret_cast<const f4*>(p + 4);
    bf16x8 r;
    r[0] = f2bf(a.x); r[1] = f2bf(a.y); r[2] = f2bf(a.z); r[3] = f2bf(a.w);
    r[4] = f2bf(b.x); r[5] = f2bf(b.y); r[6] = f2bf(b.z); r[7] = f2bf(b.w);
    return r;
}

// ---------------------------------------------------------------------------
// Kernel 1: six GEMMs via bf16 MFMA (unchanged from R4 — ~5-8 us).
// ---------------------------------------------------------------------------
__global__ __launch_bounds__(256) void gemm6_mfma(
    const float* __restrict__ x,
    const float* __restrict__ Wq, const float* __restrict__ bq,
    const float* __restrict__ Wk, const float* __restrict__ bk,
    const float* __restrict__ Wv, const float* __restrict__ bv,
    const float* __restrict__ Wi, const float* __restrict__ bi,
    const float* __restrict__ Wf, const float* __restrict__ bf_,
    const float* __restrict__ Wo, const float* __restrict__ bo,
    float* __restrict__ pre)
{
    const int bx = blockIdx.x;
    const int g  = bx >> 6;             // gate
    const int j0 = (bx & 63) << 4;      // 16-col tile
    const float* W; const float* bias;
    switch (g) {
        case 0: W = Wq; bias = bq; break;
        case 1: W = Wk; bias = bk; break;
        case 2: W = Wv; bias = bv; break;
        case 3: W = Wi; bias = bi; break;
        case 4: W = Wf; bias = bf_; break;
        default: W = Wo; bias = bo; break;
    }

    const int wave = threadIdx.x >> 6;
    const int lane = threadIdx.x & 63;
    const int l15  = lane & 15;
    const int kq   = lane >> 4;         // 0..3

    const float* xrow = x + (size_t)(wave * 16 + l15) * DIM + kq * 8;
    const float* wrow = W + (size_t)(j0 + l15) * DIM + kq * 8;

    f32x4 acc0 = {0.f, 0.f, 0.f, 0.f};
    f32x4 acc1 = {0.f, 0.f, 0.f, 0.f};
    #pragma unroll 4
    for (int kt = 0; kt < 32; kt += 2) {
        bf16x8 a0 = load_bf8(xrow + kt * 32);
        bf16x8 b0 = load_bf8(wrow + kt * 32);
        bf16x8 a1 = load_bf8(xrow + kt * 32 + 32);
        bf16x8 b1 = load_bf8(wrow + kt * 32 + 32);
        acc0 = __builtin_amdgcn_mfma_f32_16x16x32_bf16(a0, b0, acc0, 0, 0, 0);
        acc1 = __builtin_amdgcn_mfma_f32_16x16x32_bf16(a1, b1, acc1, 0, 0, 0);
    }
    acc0 += acc1;

    const float bv_ = bias[j0 + l15];           // D col = lane&15
    float* dst = pre + (size_t)g * NROW + (size_t)(wave * 16 + kq * 4) * DIM + j0 + l15;
    #pragma unroll
    for (int r = 0; r < 4; ++r)
        dst[(size_t)r * DIM] = acc0[r] + bv_;   // D row = kq*4 + r
}

// ---------------------------------------------------------------------------
// Kernel 2 v2.1: copy-bench-shaped streaming pass.
// 2048 blocks (64 b x 32 rowgroups) x 256 thr. Wave owns 8 contiguous rows.
// k/q frags live in REGISTERS (loop-invariant per lane); in-loop VMEM is
// purely {ld C, st C_new}, software-pipelined one row ahead.
// h uses dot(C_new,q) = fex*dot(C,q) + ksc*dot(k,q).
// FIX vs v2: each wave's 64 lanes already cover the full row, so `part` IS
// dot(k,q) — no cross-wave sum (v2 quadruple-counted it).
// ---------------------------------------------------------------------------
__global__ __launch_bounds__(256) void cupdate2(
    const float* __restrict__ C,
    const float* __restrict__ n_in, const float* __restrict__ m_in,
    const float* __restrict__ ws,
    float* __restrict__ out)
{
    const int blk  = blockIdx.x;          // 0..2047
    const int b    = blk >> 5;            // batch
    const int rg   = blk & 31;            // row-group within batch
    const int tid  = threadIdx.x;
    const int w    = tid >> 6;
    const int lane = tid & 63;

    // register-resident k (raw pre_k) and q fragments: 4 f4 each per lane
    const f4* k4g = reinterpret_cast<const f4*>(ws + 1 * NROW + b * DIM);
    const f4* q4g = reinterpret_cast<const f4*>(ws + 0 * NROW + b * DIM);
    f4 k0 = k4g[lane],       k1 = k4g[lane + 64],
       k2 = k4g[lane + 128], k3 = k4g[lane + 192];
    f4 q0 = q4g[lane],       q1 = q4g[lane + 64],
       q2 = q4g[lane + 128], q3 = q4g[lane + 192];

    // dot(k_raw, q): each wave covers the full row -> complete after shuffle
    f4 pp = k0 * q0 + k1 * q1 + k2 * q2 + k3 * q3;
    float kqdot = pp.x + pp.y + pp.z + pp.w;
    #pragma unroll
    for (int off = 32; off > 0; off >>= 1)
        kqdot += __shfl_xor(kqdot, off, 64);

    const int row0 = b * DIM + rg * 32 + w * 8;   // first of this wave's 8 rows
    const f4* Cb = reinterpret_cast<const f4*>(C) + (size_t)row0 * 256;
    f4*       Ob = reinterpret_cast<f4*>(out + OFF_C) + (size_t)row0 * 256;

    // prologue: row 0 loads
    f4 c0 = Cb[lane], c1 = Cb[lane + 64], c2 = Cb[lane + 128], c3 = Cb[lane + 192];

    #pragma unroll
    for (int r = 0; r < 8; ++r) {
        const int row = row0 + r;
        // prefetch next row while computing this one
        f4 p0, p1, p2, p3;
        if (r < 7) {
            const f4* Cn = Cb + (size_t)(r + 1) * 256;
            p0 = Cn[lane]; p1 = Cn[lane + 64]; p2 = Cn[lane + 128]; p3 = Cn[lane + 192];
        }
        // per-row gate scalars (wave-uniform broadcast loads)
        const float ip  = ws[3 * NROW + row];
        const float fp_ = ws[4 * NROW + row];
        const float op  = ws[5 * NROW + row];
        const float vp  = ws[2 * NROW + row];
        const float mo  = m_in[row];

        const float mn  = fmaxf(fp_ + mo, ip);
        const float iex = expf(ip - mn);
        const float fex = expf(fp_ + mo - mn);
        const float so  = 1.f / (1.f + expf(-op));
        const float ksc = iex * vp * 0.03125f;    // i*v*(1/sqrt(DIM))

        f4* Or = Ob + (size_t)r * 256;
        Or[lane]       = fex * c0 + ksc * k0;
        Or[lane + 64]  = fex * c1 + ksc * k1;
        Or[lane + 128] = fex * c2 + ksc * k2;
        Or[lane + 192] = fex * c3 + ksc * k3;

        // dot(C_old, q) for h (identity: dot(C_new,q) = fex*dotCq + ksc*kqdot)
        f4 d = c0 * q0 + c1 * q1 + c2 * q2 + c3 * q3;
        float dot = d.x + d.y + d.z + d.w;
        #pragma unroll
        for (int off = 32; off > 0; off >>= 1)
            dot += __shfl_xor(dot, off, 64);

        if (lane == 0) {
            out[OFF_H + row] = so * (fex * dot + ksc * kqdot);
            out[OFF_N + row] = fex * n_in[row] + iex * ws[1 * NROW + row] * 0.03125f;
            out[OFF_M + row] = mn;
        }
        c0 = p0; c1 = p1; c2 = p2; c3 = p3;
    }
}

extern "C" void kernel_launch(void* const* d_in, const int* in_sizes, int n_in,
                              void* d_out, int out_size, void* d_ws, size_t ws_size,
                              hipStream_t stream) {
    const float* x = (const float*)d_in[0];
    const float* C = (const float*)d_in[1];
    const float* n = (const float*)d_in[2];
    const float* m = (const float*)d_in[3];
    float* ws  = (float*)d_ws;    // needs 6*65536*4 = 1.5 MB
    float* out = (float*)d_out;

    gemm6_mfma<<<384, 256, 0, stream>>>(
        x,
        (const float*)d_in[4],  (const float*)d_in[5],
        (const float*)d_in[6],  (const float*)d_in[7],
        (const float*)d_in[8],  (const float*)d_in[9],
        (const float*)d_in[10], (const float*)d_in[11],
        (const float*)d_in[12], (const float*)d_in[13],
        (const float*)d_in[14], (const float*)d_in[15],
        ws);
    cupdate2<<<2048, 256, 0, stream>>>(C, n, m, ws, out);
}

// Round 7
// 132.530 us; speedup vs baseline: 1.0317x; 1.0317x over previous
//
#include <hip/hip_runtime.h>
#include <hip/hip_bf16.h>
#include <math.h>

#define BATCH 64
#define DIM 1024
#define NROW (BATCH * DIM)        // 65536 rows of C
// d_out layout (floats): h[65536] | C_new[67108864] | n_new[65536] | m_new[65536]
#define OFF_H 0
#define OFF_C 65536
#define OFF_N (65536 + 67108864)
#define OFF_M (OFF_N + 65536)

typedef float f4     __attribute__((ext_vector_type(4)));
typedef float f32x4  __attribute__((ext_vector_type(4)));   // MFMA C/D frag
typedef short bf16x8 __attribute__((ext_vector_type(8)));   // MFMA A/B frag (8 bf16)

// ws layout (floats): pre[6][NROW], gate order 0:q 1:k 2:v 3:i 4:f 5:o

__device__ inline short f2bf(float v) {
    __hip_bfloat16 h = __float2bfloat16(v);   // RNE convert
    short s;
    __builtin_memcpy(&s, &h, 2);
    return s;
}

__device__ inline bf16x8 load_bf8(const float* __restrict__ p) {
    f4 a = *reinterpret_cast<const f4*>(p);
    f4 b = *reinterpret_cast<const f4*>(p + 4);
    bf16x8 r;
    r[0] = f2bf(a.x); r[1] = f2bf(a.y); r[2] = f2bf(a.z); r[3] = f2bf(a.w);
    r[4] = f2bf(b.x); r[5] = f2bf(b.y); r[6] = f2bf(b.z); r[7] = f2bf(b.w);
    return r;
}

__device__ inline int   biti(float f) { int i;   __builtin_memcpy(&i, &f, 4); return i; }
__device__ inline float bitf(int i)   { float f; __builtin_memcpy(&f, &i, 4); return f; }

// Canonical GCN wave-64 sum via DPP: 4x row_shr + row_bcast15 + row_bcast31.
// ~6 VALU-latency dependent ops (vs 6 LDS-latency ds_bpermute for __shfl_xor).
// Result (total) returned wave-uniform via readlane 63.
__device__ inline float wave_sum64_dpp(float x) {
    int t;
    t = __builtin_amdgcn_update_dpp(0, biti(x), 0x111, 0xF, 0xF, true); x += bitf(t); // row_shr:1
    t = __builtin_amdgcn_update_dpp(0, biti(x), 0x112, 0xF, 0xF, true); x += bitf(t); // row_shr:2
    t = __builtin_amdgcn_update_dpp(0, biti(x), 0x114, 0xF, 0xF, true); x += bitf(t); // row_shr:4
    t = __builtin_amdgcn_update_dpp(0, biti(x), 0x118, 0xF, 0xF, true); x += bitf(t); // row_shr:8
    t = __builtin_amdgcn_update_dpp(0, biti(x), 0x142, 0xA, 0xF, true); x += bitf(t); // row_bcast:15
    t = __builtin_amdgcn_update_dpp(0, biti(x), 0x143, 0xC, 0xF, true); x += bitf(t); // row_bcast:31
    return bitf(__builtin_amdgcn_readlane(biti(x), 63));
}

// ---------------------------------------------------------------------------
// Kernel 1: six GEMMs via bf16 MFMA (unchanged from R4 — ~5-8 us).
// ---------------------------------------------------------------------------
__global__ __launch_bounds__(256) void gemm6_mfma(
    const float* __restrict__ x,
    const float* __restrict__ Wq, const float* __restrict__ bq,
    const float* __restrict__ Wk, const float* __restrict__ bk,
    const float* __restrict__ Wv, const float* __restrict__ bv,
    const float* __restrict__ Wi, const float* __restrict__ bi,
    const float* __restrict__ Wf, const float* __restrict__ bf_,
    const float* __restrict__ Wo, const float* __restrict__ bo,
    float* __restrict__ pre)
{
    const int bx = blockIdx.x;
    const int g  = bx >> 6;             // gate
    const int j0 = (bx & 63) << 4;      // 16-col tile
    const float* W; const float* bias;
    switch (g) {
        case 0: W = Wq; bias = bq; break;
        case 1: W = Wk; bias = bk; break;
        case 2: W = Wv; bias = bv; break;
        case 3: W = Wi; bias = bi; break;
        case 4: W = Wf; bias = bf_; break;
        default: W = Wo; bias = bo; break;
    }

    const int wave = threadIdx.x >> 6;
    const int lane = threadIdx.x & 63;
    const int l15  = lane & 15;
    const int kq   = lane >> 4;         // 0..3

    const float* xrow = x + (size_t)(wave * 16 + l15) * DIM + kq * 8;
    const float* wrow = W + (size_t)(j0 + l15) * DIM + kq * 8;

    f32x4 acc0 = {0.f, 0.f, 0.f, 0.f};
    f32x4 acc1 = {0.f, 0.f, 0.f, 0.f};
    #pragma unroll 4
    for (int kt = 0; kt < 32; kt += 2) {
        bf16x8 a0 = load_bf8(xrow + kt * 32);
        bf16x8 b0 = load_bf8(wrow + kt * 32);
        bf16x8 a1 = load_bf8(xrow + kt * 32 + 32);
        bf16x8 b1 = load_bf8(wrow + kt * 32 + 32);
        acc0 = __builtin_amdgcn_mfma_f32_16x16x32_bf16(a0, b0, acc0, 0, 0, 0);
        acc1 = __builtin_amdgcn_mfma_f32_16x16x32_bf16(a1, b1, acc1, 0, 0, 0);
    }
    acc0 += acc1;

    const float bv_ = bias[j0 + l15];           // D col = lane&15
    float* dst = pre + (size_t)g * NROW + (size_t)(wave * 16 + kq * 4) * DIM + j0 + l15;
    #pragma unroll
    for (int r = 0; r < 4; ++r)
        dst[(size_t)r * DIM] = acc0[r] + bv_;   // D row = kq*4 + r
}

// ---------------------------------------------------------------------------
// Kernel 2 v3: lean v1 shape (1 row/wave, 16384x256) + DPP wave reduction.
// Per wave: 4 C-loads, 4 k, 4 q (L1/L2-hot), 4 stores.
//   C_new = fex*C + ksc*k_raw;   h = so*(fex*dot(C,q) + ksc*dot(k_raw,q))
// The dot uses the C LOADS (identity), decoupling it from the store stream.
// Reduce tail: ~40 cyc DPP instead of ~250 cyc ds_bpermute chain.
// ---------------------------------------------------------------------------
__global__ __launch_bounds__(256) void cupdate3(
    const float* __restrict__ C,
    const float* __restrict__ n_in, const float* __restrict__ m_in,
    const float* __restrict__ ws,
    float* __restrict__ out)
{
    const int row  = blockIdx.x * 4 + (threadIdx.x >> 6);   // 0..65535
    const int lane = threadIdx.x & 63;
    const int b    = row >> 10;

    // per-row gate scalars (wave-uniform broadcast loads)
    const float ip  = ws[3 * NROW + row];
    const float fp_ = ws[4 * NROW + row];
    const float op  = ws[5 * NROW + row];
    const float vp  = ws[2 * NROW + row];
    const float mo  = m_in[row];

    const float mn  = fmaxf(fp_ + mo, ip);
    const float iex = expf(ip - mn);
    const float fex = expf(fp_ + mo - mn);
    const float so  = 1.f / (1.f + expf(-op));
    const float ksc = iex * vp * 0.03125f;    // i*v*(1/sqrt(DIM))

    const f4* k4 = reinterpret_cast<const f4*>(ws + 1 * NROW + b * DIM); // pre_k (raw)
    const f4* q4 = reinterpret_cast<const f4*>(ws + 0 * NROW + b * DIM); // q
    const f4* C4 = reinterpret_cast<const f4*>(C) + (size_t)row * 256;
    f4*       O4 = reinterpret_cast<f4*>(out + OFF_C) + (size_t)row * 256;

    float dotC = 0.f, dotK = 0.f;
    #pragma unroll
    for (int i = 0; i < 4; ++i) {
        const int c4 = lane + 64 * i;          // float4 column index, coalesced
        f4 cv = C4[c4];
        f4 kv = k4[c4];
        f4 qv = q4[c4];
        O4[c4] = fex * cv + ksc * kv;
        f4 pc = cv * qv;
        f4 pk = kv * qv;
        dotC += pc.x + pc.y + pc.z + pc.w;
        dotK += pk.x + pk.y + pk.z + pk.w;
    }

    const float dC = wave_sum64_dpp(dotC);
    const float dK = wave_sum64_dpp(dotK);

    if (lane == 0) {
        out[OFF_H + row] = so * (fex * dC + ksc * dK);
        out[OFF_N + row] = fex * n_in[row] + iex * ws[1 * NROW + row] * 0.03125f;
        out[OFF_M + row] = mn;
    }
}

extern "C" void kernel_launch(void* const* d_in, const int* in_sizes, int n_in,
                              void* d_out, int out_size, void* d_ws, size_t ws_size,
                              hipStream_t stream) {
    const float* x = (const float*)d_in[0];
    const float* C = (const float*)d_in[1];
    const float* n = (const float*)d_in[2];
    const float* m = (const float*)d_in[3];
    float* ws  = (float*)d_ws;    // needs 6*65536*4 = 1.5 MB
    float* out = (float*)d_out;

    gemm6_mfma<<<384, 256, 0, stream>>>(
        x,
        (const float*)d_in[4],  (const float*)d_in[5],
        (const float*)d_in[6],  (const float*)d_in[7],
        (const float*)d_in[8],  (const float*)d_in[9],
        (const float*)d_in[10], (const float*)d_in[11],
        (const float*)d_in[12], (const float*)d_in[13],
        (const float*)d_in[14], (const float*)d_in[15],
        ws);
    cupdate3<<<NROW / 4, 256, 0, stream>>>(C, n, m, ws, out);
}

// Round 8
// 118.144 us; speedup vs baseline: 1.1574x; 1.1218x over previous
//
#include <hip/hip_runtime.h>
#include <hip/hip_bf16.h>
#include <math.h>

#define BATCH 64
#define DIM 1024
#define NROW (BATCH * DIM)        // 65536 rows of C
// d_out layout (floats): h[65536] | C_new[67108864] | n_new[65536] | m_new[65536]
#define OFF_H 0
#define OFF_C 65536
#define OFF_N (65536 + 67108864)
#define OFF_M (OFF_N + 65536)

typedef float f4     __attribute__((ext_vector_type(4)));
typedef float f32x4  __attribute__((ext_vector_type(4)));   // MFMA C/D frag
typedef short bf16x8 __attribute__((ext_vector_type(8)));   // MFMA A/B frag (8 bf16)

// ws layout (floats): pre[6][NROW], gate order 0:q 1:k 2:v 3:i 4:f 5:o

__device__ inline short f2bf(float v) {
    __hip_bfloat16 h = __float2bfloat16(v);   // RNE convert
    short s;
    __builtin_memcpy(&s, &h, 2);
    return s;
}

__device__ inline bf16x8 load_bf8(const float* __restrict__ p) {
    f4 a = *reinterpret_cast<const f4*>(p);
    f4 b = *reinterpret_cast<const f4*>(p + 4);
    bf16x8 r;
    r[0] = f2bf(a.x); r[1] = f2bf(a.y); r[2] = f2bf(a.z); r[3] = f2bf(a.w);
    r[4] = f2bf(b.x); r[5] = f2bf(b.y); r[6] = f2bf(b.z); r[7] = f2bf(b.w);
    return r;
}

__device__ inline int   biti(float f) { int i;   __builtin_memcpy(&i, &f, 4); return i; }
__device__ inline float bitf(int i)   { float f; __builtin_memcpy(&f, &i, 4); return f; }

// Wave-64 sum via DPP (row_shr x4 + row_bcast15 + row_bcast31), wave-uniform
// result from readlane 63. ~6 VALU-latency deps.
__device__ inline float wave_sum64_dpp(float x) {
    int t;
    t = __builtin_amdgcn_update_dpp(0, biti(x), 0x111, 0xF, 0xF, true); x += bitf(t);
    t = __builtin_amdgcn_update_dpp(0, biti(x), 0x112, 0xF, 0xF, true); x += bitf(t);
    t = __builtin_amdgcn_update_dpp(0, biti(x), 0x114, 0xF, 0xF, true); x += bitf(t);
    t = __builtin_amdgcn_update_dpp(0, biti(x), 0x118, 0xF, 0xF, true); x += bitf(t);
    t = __builtin_amdgcn_update_dpp(0, biti(x), 0x142, 0xA, 0xF, true); x += bitf(t);
    t = __builtin_amdgcn_update_dpp(0, biti(x), 0x143, 0xC, 0xF, true); x += bitf(t);
    return bitf(__builtin_amdgcn_readlane(biti(x), 63));
}

// ---------------------------------------------------------------------------
// Kernel 1: six GEMMs via bf16 MFMA (unchanged from R4 — ~5-8 us).
// ---------------------------------------------------------------------------
__global__ __launch_bounds__(256) void gemm6_mfma(
    const float* __restrict__ x,
    const float* __restrict__ Wq, const float* __restrict__ bq,
    const float* __restrict__ Wk, const float* __restrict__ bk,
    const float* __restrict__ Wv, const float* __restrict__ bv,
    const float* __restrict__ Wi, const float* __restrict__ bi,
    const float* __restrict__ Wf, const float* __restrict__ bf_,
    const float* __restrict__ Wo, const float* __restrict__ bo,
    float* __restrict__ pre)
{
    const int bx = blockIdx.x;
    const int g  = bx >> 6;             // gate
    const int j0 = (bx & 63) << 4;      // 16-col tile
    const float* W; const float* bias;
    switch (g) {
        case 0: W = Wq; bias = bq; break;
        case 1: W = Wk; bias = bk; break;
        case 2: W = Wv; bias = bv; break;
        case 3: W = Wi; bias = bi; break;
        case 4: W = Wf; bias = bf_; break;
        default: W = Wo; bias = bo; break;
    }

    const int wave = threadIdx.x >> 6;
    const int lane = threadIdx.x & 63;
    const int l15  = lane & 15;
    const int kq   = lane >> 4;         // 0..3

    const float* xrow = x + (size_t)(wave * 16 + l15) * DIM + kq * 8;
    const float* wrow = W + (size_t)(j0 + l15) * DIM + kq * 8;

    f32x4 acc0 = {0.f, 0.f, 0.f, 0.f};
    f32x4 acc1 = {0.f, 0.f, 0.f, 0.f};
    #pragma unroll 4
    for (int kt = 0; kt < 32; kt += 2) {
        bf16x8 a0 = load_bf8(xrow + kt * 32);
        bf16x8 b0 = load_bf8(wrow + kt * 32);
        bf16x8 a1 = load_bf8(xrow + kt * 32 + 32);
        bf16x8 b1 = load_bf8(wrow + kt * 32 + 32);
        acc0 = __builtin_amdgcn_mfma_f32_16x16x32_bf16(a0, b0, acc0, 0, 0, 0);
        acc1 = __builtin_amdgcn_mfma_f32_16x16x32_bf16(a1, b1, acc1, 0, 0, 0);
    }
    acc0 += acc1;

    const float bv_ = bias[j0 + l15];           // D col = lane&15
    float* dst = pre + (size_t)g * NROW + (size_t)(wave * 16 + kq * 4) * DIM + j0 + l15;
    #pragma unroll
    for (int r = 0; r < 4; ++r)
        dst[(size_t)r * DIM] = acc0[r] + bv_;   // D row = kq*4 + r
}

// ---------------------------------------------------------------------------
// Kernel 2 v4: copy-shaped stream.
// 2048 blocks (64 b x 32 rows each) x 256 thr; wave owns 8 rows.
// Prologue: k/q staged to LDS; per-row gate scalars (fex,ksc,so) to LDS by
// 32 threads (n_new/m_new written here); kqdot once per wave.
// Hot loop per row: 4x {nt-load C, FMA, store C_new, dot-FMA} — the only
// global ops are the C stream itself. k/q frags hoisted to 8 regs.
// h = so*(fex*dot(C_old,q) + ksc*kqdot)   [batch-level kqdot identity]
// ---------------------------------------------------------------------------
#define RPB 32   // rows per block
__global__ __launch_bounds__(256) void cupdate4(
    const float* __restrict__ C,
    const float* __restrict__ n_in, const float* __restrict__ m_in,
    const float* __restrict__ ws,
    float* __restrict__ out)
{
    __shared__ float kq[2][DIM];          // k_raw, q  (8 KB)
    __shared__ float s_fex[RPB], s_ksc[RPB], s_so[RPB];

    const int blk  = blockIdx.x;          // 0..2047
    const int b    = blk >> 5;            // batch
    const int rg   = blk & 31;            // row-group
    const int tid  = threadIdx.x;
    const int w    = tid >> 6;
    const int lane = tid & 63;

    // stage k (raw pre_k) and q: 256 f4 each, one f4 per thread
    reinterpret_cast<f4*>(kq[0])[tid] = reinterpret_cast<const f4*>(ws + 1 * NROW + b * DIM)[tid];
    reinterpret_cast<f4*>(kq[1])[tid] = reinterpret_cast<const f4*>(ws + 0 * NROW + b * DIM)[tid];

    // per-row gate scalars + n_new/m_new (32 rows, threads 0..31)
    if (tid < RPB) {
        const int row = b * DIM + rg * RPB + tid;
        const float ip  = ws[3 * NROW + row];
        const float fp_ = ws[4 * NROW + row];
        const float op  = ws[5 * NROW + row];
        const float vp  = ws[2 * NROW + row];
        const float mo  = m_in[row];
        const float mn  = fmaxf(fp_ + mo, ip);
        const float iex = expf(ip - mn);
        const float fex = expf(fp_ + mo - mn);
        s_fex[tid] = fex;
        s_ksc[tid] = iex * vp * 0.03125f;
        s_so[tid]  = 1.f / (1.f + expf(-op));
        out[OFF_N + row] = fex * n_in[row] + iex * ws[1 * NROW + row] * 0.03125f;
        out[OFF_M + row] = mn;
    }
    __syncthreads();

    // hoist k/q fragments to registers (row-invariant)
    const f4* kl = reinterpret_cast<const f4*>(kq[0]);
    const f4* ql = reinterpret_cast<const f4*>(kq[1]);
    f4 k0 = kl[lane],       k1 = kl[lane + 64],
       k2 = kl[lane + 128], k3 = kl[lane + 192];
    f4 q0 = ql[lane],       q1 = ql[lane + 64],
       q2 = ql[lane + 128], q3 = ql[lane + 192];

    // batch-level dot(k_raw, q): once per wave
    f4 pp = k0 * q0 + k1 * q1 + k2 * q2 + k3 * q3;
    const float kqdot = wave_sum64_dpp(pp.x + pp.y + pp.z + pp.w);

    const int grow0 = b * DIM + rg * RPB + w * 8;   // wave's first row
    const f4* C4 = reinterpret_cast<const f4*>(C) + (size_t)grow0 * 256;
    f4*       O4 = reinterpret_cast<f4*>(out + OFF_C) + (size_t)grow0 * 256;

    #pragma unroll 2
    for (int rr = 0; rr < 8; ++rr) {
        const float fex = s_fex[w * 8 + rr];
        const float ksc = s_ksc[w * 8 + rr];
        const float so  = s_so[w * 8 + rr];

        const int base = rr * 256 + lane;
        f4 c0 = __builtin_nontemporal_load(&C4[base]);
        f4 c1 = __builtin_nontemporal_load(&C4[base + 64]);
        f4 c2 = __builtin_nontemporal_load(&C4[base + 128]);
        f4 c3 = __builtin_nontemporal_load(&C4[base + 192]);

        O4[base]       = fex * c0 + ksc * k0;
        O4[base + 64]  = fex * c1 + ksc * k1;
        O4[base + 128] = fex * c2 + ksc * k2;
        O4[base + 192] = fex * c3 + ksc * k3;

        f4 d = c0 * q0 + c1 * q1 + c2 * q2 + c3 * q3;
        const float dC = wave_sum64_dpp(d.x + d.y + d.z + d.w);
        if (lane == 0)
            out[OFF_H + grow0 + rr] = so * (fex * dC + ksc * kqdot);
    }
}

extern "C" void kernel_launch(void* const* d_in, const int* in_sizes, int n_in,
                              void* d_out, int out_size, void* d_ws, size_t ws_size,
                              hipStream_t stream) {
    const float* x = (const float*)d_in[0];
    const float* C = (const float*)d_in[1];
    const float* n = (const float*)d_in[2];
    const float* m = (const float*)d_in[3];
    float* ws  = (float*)d_ws;    // needs 6*65536*4 = 1.5 MB
    float* out = (float*)d_out;

    gemm6_mfma<<<384, 256, 0, stream>>>(
        x,
        (const float*)d_in[4],  (const float*)d_in[5],
        (const float*)d_in[6],  (const float*)d_in[7],
        (const float*)d_in[8],  (const float*)d_in[9],
        (const float*)d_in[10], (const float*)d_in[11],
        (const float*)d_in[12], (const float*)d_in[13],
        (const float*)d_in[14], (const float*)d_in[15],
        ws);
    cupdate4<<<2048, 256, 0, stream>>>(C, n, m, ws, out);
}